// Round 4
// baseline (321.277 us; speedup 1.0000x reference)
//
#include <hip/hip_runtime.h>

#define N_NODES 50000
#define N_EDGES 400000
#define DIM 32

typedef float f32x4 __attribute__((ext_vector_type(4)));

// ---------------------------------------------------------------------------
// Kernel 1: zero the output accumulator (d_out) and the per-node edge counter
// ---------------------------------------------------------------------------
__global__ void init_kernel(float4* __restrict__ out4, int* __restrict__ cnt) {
    int i = blockIdx.x * blockDim.x + threadIdx.x;
    if (i < N_NODES * DIM / 4) out4[i] = make_float4(0.f, 0.f, 0.f, 0.f);
    if (i < N_NODES) cnt[i] = 0;
}

// ---------------------------------------------------------------------------
// Kernel 2: in-degree histogram over dst (cnt must be zeroed first).
// Warms L2/L3 with edge_index for the edge kernel as a side effect.
// ---------------------------------------------------------------------------
__global__ void hist_kernel(const int* __restrict__ edge_index,
                            int* __restrict__ cnt) {
    int i = blockIdx.x * blockDim.x + threadIdx.x;
    if (i < N_EDGES) atomicAdd(&cnt[edge_index[2 * i + 1]], 1);
}

// ---------------------------------------------------------------------------
// Kernel 3: per-edge msg = (x_src^T * A_e) / max(cnt[dst],1), atomically
// scatter-added into out. 8 lanes per edge; lane sub = t&7 owns k-quad
// [4*sub, 4*sub+3]. Per d, the 8 lanes read one contiguous 128B row of A_e
// (f32x4/lane). a_in is streamed ONCE -> non-temporal loads keep L2/L3
// resident for node_states (x gather), cnt, and out (atomic RMW target).
// Scaling by 1/cnt here removes the separate divide pass entirely; r is
// identical for all contributions to a node, so the result matches
// (sum msg)/cnt to within fp rounding.
// ---------------------------------------------------------------------------
__global__ __launch_bounds__(256) void edge_kernel(
    const float* __restrict__ node_states,
    const float* __restrict__ a_in,
    const int*   __restrict__ edge_index,
    const int*   __restrict__ cnt,
    float* __restrict__ out_sum)
{
    int t = blockIdx.x * blockDim.x + threadIdx.x;
    int e = t >> 3;                 // edge id (grid sized exactly: no tail)
    int sub = t & 7;                // k-quad index within edge
    int lane = threadIdx.x & 63;
    int gbase = lane & 56;          // first lane of this 8-lane group

    int src = edge_index[2 * e + 0];
    int dst = edge_index[2 * e + 1];

    // x fragment: 4 consecutive d-values of x_src live in this lane
    f32x4 x4 = *reinterpret_cast<const f32x4*>(node_states + src * DIM + sub * 4);

    // A base for this lane's k-quad; row stride DIM floats = 8 f32x4
    const f32x4* A = reinterpret_cast<const f32x4*>(
        a_in + (size_t)e * (DIM * DIM) + sub * 4);

    f32x4 acc = (f32x4)(0.f);

#pragma unroll
    for (int dq = 0; dq < 8; ++dq) {
        int sl = gbase | dq;
        float x0 = __shfl(x4.x, sl, 64);   // x[4*dq + 0]
        float x1 = __shfl(x4.y, sl, 64);   // x[4*dq + 1]
        float x2 = __shfl(x4.z, sl, 64);   // x[4*dq + 2]
        float x3 = __shfl(x4.w, sl, 64);   // x[4*dq + 3]

        f32x4 a0 = __builtin_nontemporal_load(&A[(4 * dq + 0) * 8]);
        f32x4 a1 = __builtin_nontemporal_load(&A[(4 * dq + 1) * 8]);
        f32x4 a2 = __builtin_nontemporal_load(&A[(4 * dq + 2) * 8]);
        f32x4 a3 = __builtin_nontemporal_load(&A[(4 * dq + 3) * 8]);

        acc += x0 * a0;
        acc += x1 * a1;
        acc += x2 * a2;
        acc += x3 * a3;
    }

    // per-edge mean scaling (cnt finalized by hist_kernel)
    float r = 1.0f / fmaxf((float)cnt[dst], 1.0f);
    acc *= r;

    float* o = out_sum + (size_t)dst * DIM + sub * 4;
    atomicAdd(o + 0, acc.x);
    atomicAdd(o + 1, acc.y);
    atomicAdd(o + 2, acc.z);
    atomicAdd(o + 3, acc.w);
}

extern "C" void kernel_launch(void* const* d_in, const int* in_sizes, int n_in,
                              void* d_out, int out_size, void* d_ws, size_t ws_size,
                              hipStream_t stream) {
    const float* node_states = (const float*)d_in[0];
    const float* a_in        = (const float*)d_in[1];
    const int*   edge_index  = (const int*)d_in[2];   // integer inputs -> int32
    float* out = (float*)d_out;
    int*   cnt = (int*)d_ws;

    int vec_elems  = N_NODES * DIM / 4;                // 400000
    int vec_blocks = (vec_elems + 255) / 256;          // 1563
    init_kernel<<<vec_blocks, 256, 0, stream>>>((float4*)out, cnt);

    hist_kernel<<<(N_EDGES + 255) / 256, 256, 0, stream>>>(edge_index, cnt);

    int edge_threads = N_EDGES * 8;                    // 3.2M, exact multiple of 256
    edge_kernel<<<edge_threads / 256, 256, 0, stream>>>(
        node_states, a_in, edge_index, cnt, out);
}

// Round 5
// 314.821 us; speedup vs baseline: 1.0205x; 1.0205x over previous
//
#include <hip/hip_runtime.h>

#define N_NODES 50000
#define N_EDGES 400000
#define DIM 32

typedef float f32x4 __attribute__((ext_vector_type(4)));

// ---------------------------------------------------------------------------
// Kernel 1: zero the output accumulator (d_out) and the per-node edge counter
// ---------------------------------------------------------------------------
__global__ void zero_kernel(float4* __restrict__ out4, int* __restrict__ cnt) {
    int i = blockIdx.x * blockDim.x + threadIdx.x;
    if (i < N_NODES * DIM / 4) out4[i] = make_float4(0.f, 0.f, 0.f, 0.f);
    if (i < N_NODES) cnt[i] = 0;
}

// ---------------------------------------------------------------------------
// Kernel 2: per-edge msg = x_src^T * A_e, atomically scatter-added into out.
// 8 lanes per edge; lane sub = t&7 owns k-quad [4*sub, 4*sub+3].
// Per d, the 8 lanes read one contiguous 128B row of A_e (f32x4/lane).
// a_in and edge_index are streamed ONCE -> non-temporal loads keep L2/L3
// resident for node_states (x gather) and out (atomic RMW target).
// ---------------------------------------------------------------------------
__global__ __launch_bounds__(256) void edge_kernel(
    const float* __restrict__ node_states,
    const float* __restrict__ a_in,
    const int*   __restrict__ edge_index,
    float* __restrict__ out_sum,
    int*   __restrict__ cnt)
{
    int t = blockIdx.x * blockDim.x + threadIdx.x;
    int e = t >> 3;                 // edge id (grid sized exactly: no tail)
    int sub = t & 7;                // k-quad index within edge
    int lane = threadIdx.x & 63;
    int gbase = lane & 56;          // first lane of this 8-lane group

    int src = __builtin_nontemporal_load(edge_index + 2 * e + 0);
    int dst = __builtin_nontemporal_load(edge_index + 2 * e + 1);

    // x fragment: 4 consecutive d-values of x_src live in this lane
    f32x4 x4 = *reinterpret_cast<const f32x4*>(node_states + src * DIM + sub * 4);

    // A base for this lane's k-quad; row stride DIM floats = 8 f32x4
    const f32x4* A = reinterpret_cast<const f32x4*>(
        a_in + (size_t)e * (DIM * DIM) + sub * 4);

    f32x4 acc = (f32x4)(0.f);

#pragma unroll
    for (int dq = 0; dq < 8; ++dq) {
        int sl = gbase | dq;
        float x0 = __shfl(x4.x, sl, 64);   // x[4*dq + 0]
        float x1 = __shfl(x4.y, sl, 64);   // x[4*dq + 1]
        float x2 = __shfl(x4.z, sl, 64);   // x[4*dq + 2]
        float x3 = __shfl(x4.w, sl, 64);   // x[4*dq + 3]

        f32x4 a0 = __builtin_nontemporal_load(&A[(4 * dq + 0) * 8]);
        f32x4 a1 = __builtin_nontemporal_load(&A[(4 * dq + 1) * 8]);
        f32x4 a2 = __builtin_nontemporal_load(&A[(4 * dq + 2) * 8]);
        f32x4 a3 = __builtin_nontemporal_load(&A[(4 * dq + 3) * 8]);

        acc += x0 * a0;
        acc += x1 * a1;
        acc += x2 * a2;
        acc += x3 * a3;
    }

    float* o = out_sum + (size_t)dst * DIM + sub * 4;
    atomicAdd(o + 0, acc.x);
    atomicAdd(o + 1, acc.y);
    atomicAdd(o + 2, acc.z);
    atomicAdd(o + 3, acc.w);
    if (sub == 0) atomicAdd(&cnt[dst], 1);
}

// ---------------------------------------------------------------------------
// Kernel 3: out[n,k] /= max(cnt[n], 1)   (float4-vectorized, NT store:
// final output, never re-read on device)
// ---------------------------------------------------------------------------
__global__ void div_kernel(f32x4* __restrict__ out4, const int* __restrict__ cnt) {
    int i = blockIdx.x * blockDim.x + threadIdx.x;   // one float4 per thread
    if (i < N_NODES * DIM / 4) {
        float c = fmaxf((float)cnt[i >> 3], 1.0f);   // 8 float4 per node
        float r = 1.0f / c;
        f32x4 v = out4[i];
        v *= r;
        __builtin_nontemporal_store(v, &out4[i]);
    }
}

extern "C" void kernel_launch(void* const* d_in, const int* in_sizes, int n_in,
                              void* d_out, int out_size, void* d_ws, size_t ws_size,
                              hipStream_t stream) {
    const float* node_states = (const float*)d_in[0];
    const float* a_in        = (const float*)d_in[1];
    const int*   edge_index  = (const int*)d_in[2];   // integer inputs -> int32
    float* out = (float*)d_out;
    int*   cnt = (int*)d_ws;

    int vec_elems  = N_NODES * DIM / 4;                // 400000
    int vec_blocks = (vec_elems + 255) / 256;          // 1563
    zero_kernel<<<vec_blocks, 256, 0, stream>>>((float4*)out, cnt);

    int edge_threads = N_EDGES * 8;                    // 3.2M, exact multiple of 256
    edge_kernel<<<edge_threads / 256, 256, 0, stream>>>(
        node_states, a_in, edge_index, out, cnt);

    div_kernel<<<vec_blocks, 256, 0, stream>>>((f32x4*)out, cnt);
}